// Round 1
// baseline (203.203 us; speedup 1.0000x reference)
//
#include <hip/hip_runtime.h>
#include <math.h>

// Problem constants (from reference): N=100000, S=64, Q=50, P=3
#define N_Q 50
#define N_P 3
#define N_S 64
#define ROW 150        // Q*P floats per pauli word
#define BLK_ROWS 128   // rows per block (2 per lane)
#define THREADS 512    // 8 waves; wave w handles s in [8w, 8w+8)
#define WAVES 8
#define SCHUNK 8
// Padded LDS q-row: 64*3=192 words + 4 pad = 196 words (784 B).
// 196 % 32 == 4 -> staging writes spread over 8 banks (8-way worst case);
// main-loop reads are wave-uniform broadcasts (conflict-free) and stay
// 16B-aligned (196 % 4 == 0 -> 49 float4 per q-row).
#define QPAD 196

// ws layout (bytes):
//   [0      .. 6256)    partials double[782]
//   [6272   .. +4)      done-counter int (zeroed via hipMemsetAsync each launch)
#define WS_CNT_OFF 6272

__device__ __forceinline__ float softplus20(float x) {
    float z = x * 20.0f;
    return fmaxf(z, 0.0f) + log1pf(expf(-fabsf(z)));  // stable softplus
}

// One q, 8 s-values (2 groups of 4), applied to TWO rows sharing the H regs.
__device__ __forceinline__ void computeQ2(const float4* __restrict__ Hq,
                                          float a0, float a1, float a2,
                                          float c0, float c1, float c2,
                                          float (&p)[SCHUNK], float (&p2)[SCHUNK]) {
    #pragma unroll
    for (int g = 0; g < SCHUNK / 4; ++g) {
        float4 b0 = Hq[3 * g], b1 = Hq[3 * g + 1], b2 = Hq[3 * g + 2];
        // layout per 4 s: [h00 h01 h02 h10][h11 h12 h20 h21][h22 h30 h31 h32]
        p [4*g+0] *= fmaf(b0.x, a0, fmaf(b0.y, a1, b0.z * a2));
        p2[4*g+0] *= fmaf(b0.x, c0, fmaf(b0.y, c1, b0.z * c2));
        p [4*g+1] *= fmaf(b0.w, a0, fmaf(b1.x, a1, b1.y * a2));
        p2[4*g+1] *= fmaf(b0.w, c0, fmaf(b1.x, c1, b1.y * c2));
        p [4*g+2] *= fmaf(b1.z, a0, fmaf(b1.w, a1, b2.x * a2));
        p2[4*g+2] *= fmaf(b1.z, c0, fmaf(b1.w, c1, b2.x * c2));
        p [4*g+3] *= fmaf(b2.y, a0, fmaf(b2.z, a1, b2.w * a2));
        p2[4*g+3] *= fmaf(b2.y, c0, fmaf(b2.z, c1, b2.w * c2));
    }
}

__global__ __launch_bounds__(THREADS, 6) void main_kernel(
    const float* __restrict__ A, const float* __restrict__ coeff,
    const float* __restrict__ heads_param, const float* __restrict__ hr_param,
    double* __restrict__ partials, int* __restrict__ cnt,
    float* __restrict__ out, int N) {
    __shared__ float hHs[N_Q * QPAD];        // 39200 B, padded q-major
    __shared__ float hrvl[N_S];
    __shared__ float covs[WAVES][BLK_ROWS];  // 4096 B
    __shared__ double redd[2];
    __shared__ double redf[WAVES];
    __shared__ int isLast;

    const int tid = threadIdx.x;
    const int lane = tid & 63;
    const int wave = tid >> 6;
    const int nbase = blockIdx.x * BLK_ROWS;

    // --- merged precompute: softplus + L1-normalize directly into LDS ---
    if (tid < N_S) {  // wave 0 exactly: smoothed head ratios
        float sp = softplus20(hr_param[tid]);
        float tot = sp;
        #pragma unroll
        for (int off = 32; off; off >>= 1) tot += __shfl_xor(tot, off);
        float hr = sp / fmaxf(tot, 1e-12f);
        hrvl[tid] = (hr + 0.001f / (float)N_S) / 1.001f;
    }
    // EXACT reference semantics: h_p = sp_p / max(sum, EPS).
    // idx = s*Q + q -> coalesced 12 B/lane global reads; LDS writes hit the
    // padded q-major layout (8-way worst-case bank conflict, staging only).
    for (int idx = tid; idx < N_S * N_Q; idx += THREADS) {
        int s = idx / N_Q;
        int q = idx - s * N_Q;
        const float* hp = heads_param + (size_t)idx * N_P;
        float sp0 = softplus20(hp[0]);
        float sp1 = softplus20(hp[1]);
        float sp2 = softplus20(hp[2]);
        float denom = fmaxf(sp0 + sp1 + sp2, 1e-12f);
        float* o = hHs + q * QPAD + s * 3;
        o[0] = sp0 / denom;
        o[1] = sp1 / denom;
        o[2] = sp2 / denom;
    }
    __syncthreads();

    // lane owns rows n0 = nbase+lane and n1 = nbase+64+lane (same for all waves)
    int n0 = nbase + lane;        if (n0 >= N) n0 = N - 1;
    int n1 = nbase + 64 + lane;   if (n1 >= N) n1 = N - 1;
    const float2* __restrict__ pA0 = (const float2*)A + (size_t)n0 * (ROW / 2);
    const float2* __restrict__ pA1 = (const float2*)A + (size_t)n1 * (ROW / 2);

    float prod0[SCHUNK], prod1[SCHUNK];
    #pragma unroll
    for (int i = 0; i < SCHUNK; ++i) { prod0[i] = 1.0f; prod1[i] = 1.0f; }

    // H base for this wave's s-chunk: float4 offset 6*wave within each q-row
    const float4* __restrict__ Hw = (const float4*)hHs + 6 * wave;

    // window = 2 q = 6 floats/row; explicit next-window prefetch
    float2 x0 = pA0[0], x1 = pA0[1], x2 = pA0[2];
    float2 y0 = pA1[0], y1 = pA1[1], y2 = pA1[2];

    #pragma unroll 5
    for (int w = 0; w < N_Q / 2; ++w) {
        const int nb = (w < N_Q / 2 - 1) ? 3 * w + 3 : 0;  // clamped, always valid
        float2 nx0 = pA0[nb], nx1 = pA0[nb + 1], nx2 = pA0[nb + 2];
        float2 ny0 = pA1[nb], ny1 = pA1[nb + 1], ny2 = pA1[nb + 2];
        const float4* Hq = Hw + 98 * w;      // q = 2w -> row offset 2w*49
        computeQ2(Hq,      x0.x, x0.y, x1.x,  y0.x, y0.y, y1.x, prod0, prod1);
        computeQ2(Hq + 49, x1.y, x2.x, x2.y,  y1.y, y2.x, y2.y, prod0, prod1);
        x0 = nx0; x1 = nx1; x2 = nx2; y0 = ny0; y1 = ny1; y2 = ny2;
    }

    // ratio-weighted partials for both rows
    float acc0 = 0.0f, acc1 = 0.0f;
    const int s0 = wave * SCHUNK;
    #pragma unroll
    for (int i = 0; i < SCHUNK; ++i) {
        float wgt = hrvl[s0 + i];
        acc0 = fmaf(wgt, prod0[i], acc0);
        acc1 = fmaf(wgt, prod1[i], acc1);
    }
    covs[wave][lane] = acc0;
    covs[wave][64 + lane] = acc1;
    __syncthreads();

    // waves 0,1 finalize rows 0..63 / 64..127
    if (wave < 2) {
        const int row = wave * 64 + lane;
        const int n = nbase + row;
        float cov = 0.0f;
        #pragma unroll
        for (int wv = 0; wv < WAVES; ++wv) cov += covs[wv][row];
        float term = 0.0f;
        if (n < N) { float c = coeff[n]; term = (c * c) / cov; }
        double td = (double)term;
        #pragma unroll
        for (int off = 32; off; off >>= 1) td += __shfl_down(td, off);
        if (lane == 0) redd[wave] = td;
    }
    __syncthreads();

    if (tid == 0) {
        partials[blockIdx.x] = redd[0] + redd[1];
        __threadfence();                 // release partial
        int v = atomicAdd(cnt, 1);
        isLast = (v == (int)gridDim.x - 1);
    }
    __syncthreads();

    if (isLast) {                        // last-finishing block reduces all
        __threadfence();                 // acquire
        double s = 0.0;
        for (int i = tid; i < (int)gridDim.x; i += THREADS) s += partials[i];
        #pragma unroll
        for (int off = 32; off; off >>= 1) s += __shfl_down(s, off);
        if (lane == 0) redf[wave] = s;
        __syncthreads();
        if (tid == 0) {
            double t = 0.0;
            #pragma unroll
            for (int wv = 0; wv < WAVES; ++wv) t += redf[wv];
            out[0] = (float)t;
        }
    }
}

extern "C" void kernel_launch(void* const* d_in, const int* in_sizes, int n_in,
                              void* d_out, int out_size, void* d_ws, size_t ws_size,
                              hipStream_t stream) {
    const float* A           = (const float*)d_in[0];  // [N, Q, P]
    const float* coeff       = (const float*)d_in[1];  // [N]
    const float* heads_param = (const float*)d_in[2];  // [S, Q, P]
    const float* hr_param    = (const float*)d_in[3];  // [S]
    const int N = in_sizes[1];
    const int nblocks = (N + BLK_ROWS - 1) / BLK_ROWS;  // 782

    char* ws = (char*)d_ws;
    double* partials = (double*)ws;
    int*   cnt = (int*)(ws + WS_CNT_OFF);
    float* out = (float*)d_out;

    hipMemsetAsync(cnt, 0, sizeof(int), stream);  // ws is re-poisoned每 launch
    main_kernel<<<nblocks, THREADS, 0, stream>>>(A, coeff, heads_param, hr_param,
                                                 partials, cnt, out, N);
}

// Round 2
// 155.831 us; speedup vs baseline: 1.3040x; 1.3040x over previous
//
#include <hip/hip_runtime.h>
#include <math.h>

// Problem constants (from reference): N=100000, S=64, Q=50, P=3
#define N_Q 50
#define N_P 3
#define N_S 64
#define ROW 150        // Q*P floats per pauli word
#define BLK_ROWS 64    // rows per block (1 per lane)
#define THREADS 256    // 4 waves; wave w handles s in [16w, 16w+16)
#define WAVES 4
#define SCHUNK 16

// ws layout (bytes):
//   [0      .. 12504)   partials double[1563]
//   [12544  .. +4)      done-counter int (zeroed by precompute each launch)
//   [12608  .. +38400)  HP   float[Q][S][3]  normalized heads, q-major
//   [51008  .. +256)    hrv  float[S]        smoothed head ratios
#define WS_CNT_OFF 12544
#define WS_HP_OFF 12608
#define WS_HRV_OFF 51008

__device__ __forceinline__ float softplus20(float x) {
    float z = x * 20.0f;
    return fmaxf(z, 0.0f) + log1pf(expf(-fabsf(z)));  // stable softplus
}

__global__ void precompute_kernel(const float* __restrict__ heads_param,
                                  const float* __restrict__ hr_param,
                                  float* __restrict__ HP,
                                  float* __restrict__ hrv,
                                  int* __restrict__ cnt) {
    const int tid = threadIdx.x;
    if (blockIdx.x == 0) {
        if (tid == 0) *cnt = 0;  // ws is re-poisoned every launch
        if (tid < N_S) {
            float sp = softplus20(hr_param[tid]);
            float tot = sp;
            #pragma unroll
            for (int off = 32; off; off >>= 1) tot += __shfl_xor(tot, off);
            float hr = sp / fmaxf(tot, 1e-12f);
            hrv[tid] = (hr + 0.001f / (float)N_S) / 1.001f;
        }
    }
    // EXACT reference semantics: h_p = sp_p / max(sum, EPS); when the clamp
    // fires the row does NOT sum to 1, so all three components are stored.
    int idx = blockIdx.x * blockDim.x + tid;
    if (idx < N_S * N_Q) {
        int q = idx / N_S;
        int s = idx - q * N_S;
        const float* hp = heads_param + ((size_t)s * N_Q + q) * N_P;
        float sp0 = softplus20(hp[0]);
        float sp1 = softplus20(hp[1]);
        float sp2 = softplus20(hp[2]);
        float denom = fmaxf(sp0 + sp1 + sp2, 1e-12f);
        float* o = HP + ((size_t)q * N_S + s) * 3;
        o[0] = sp0 / denom;
        o[1] = sp1 / denom;
        o[2] = sp2 / denom;
    }
}

// One q, 16 s-values (4 groups of 4), ONE row per lane. Hq is a wave-uniform
// global pointer (readfirstlane'd base) -> compiler emits s_load_dwordx4/x8/x16;
// each FMA consumes one SGPR (H) + VGPRs (A), which the ISA allows.
__device__ __forceinline__ void computeQ1(const float4* __restrict__ Hq,
                                          float a0, float a1, float a2,
                                          float (&p)[SCHUNK]) {
    #pragma unroll
    for (int g = 0; g < 4; ++g) {
        float4 b0 = Hq[3 * g], b1 = Hq[3 * g + 1], b2 = Hq[3 * g + 2];
        // layout per 4 s: [h00 h01 h02 h10][h11 h12 h20 h21][h22 h30 h31 h32]
        p[4*g+0] *= fmaf(b0.x, a0, fmaf(b0.y, a1, b0.z * a2));
        p[4*g+1] *= fmaf(b0.w, a0, fmaf(b1.x, a1, b1.y * a2));
        p[4*g+2] *= fmaf(b1.z, a0, fmaf(b1.w, a1, b2.x * a2));
        p[4*g+3] *= fmaf(b2.y, a0, fmaf(b2.z, a1, b2.w * a2));
    }
}

__global__ __launch_bounds__(THREADS) void main_kernel(
    const float* __restrict__ A, const float* __restrict__ coeff,
    const float* __restrict__ HP, const float* __restrict__ hrv,
    double* __restrict__ partials, int* __restrict__ cnt,
    float* __restrict__ out, int N) {
    __shared__ float covs[WAVES][BLK_ROWS];  // 1024 B — no H tile in LDS anymore
    __shared__ double redf[WAVES];
    __shared__ int isLast;

    const int tid = threadIdx.x;
    const int lane = tid & 63;
    const int wave = tid >> 6;
    // Force the wave index into an SGPR so all H/hrv addresses are provably
    // wave-uniform -> scalar loads on the SMEM pipe, zero VALU/LDS cost.
    const int wq = __builtin_amdgcn_readfirstlane(wave);
    const int nbase = blockIdx.x * BLK_ROWS;

    // lane owns row n0 = nbase + lane (same rows for all 4 waves)
    int n0 = nbase + lane;  if (n0 >= N) n0 = N - 1;
    const float2* __restrict__ pA0 = (const float2*)A + (size_t)n0 * (ROW / 2);

    float prod[SCHUNK];
    #pragma unroll
    for (int i = 0; i < SCHUNK; ++i) prod[i] = 1.0f;

    // H base for this wave's s-chunk: q-row = 48 float4; wave offset 12*wq
    const float4* __restrict__ Hw = (const float4*)HP + 12 * wq;

    // window = 2 q = 6 floats/row; one-window A prefetch (6 floats live extra)
    float2 x0 = pA0[0], x1 = pA0[1], x2 = pA0[2];

    #pragma unroll 5
    for (int w = 0; w < N_Q / 2; ++w) {
        const int nb = (w < N_Q / 2 - 1) ? 3 * w + 3 : 0;  // clamped, always valid
        float2 nx0 = pA0[nb], nx1 = pA0[nb + 1], nx2 = pA0[nb + 2];
        const float4* Hq = Hw + 96 * w;      // q = 2w -> row offset 2w*48
        computeQ1(Hq,      x0.x, x0.y, x1.x, prod);
        computeQ1(Hq + 48, x1.y, x2.x, x2.y, prod);
        x0 = nx0; x1 = nx1; x2 = nx2;
    }

    // ratio-weighted partial for this wave's s-chunk (uniform hrv -> s_load)
    float acc = 0.0f;
    const float* __restrict__ hw = hrv + SCHUNK * wq;
    #pragma unroll
    for (int i = 0; i < SCHUNK; ++i) acc = fmaf(hw[i], prod[i], acc);
    covs[wave][lane] = acc;
    __syncthreads();

    // wave 0 finalizes all 64 rows (same s-chunking as before: bit-exact cov)
    double td = 0.0;
    if (wave == 0) {
        float cov = covs[0][lane] + covs[1][lane] + covs[2][lane] + covs[3][lane];
        float term = 0.0f;
        int n = nbase + lane;
        if (n < N) { float c = coeff[n]; term = (c * c) / cov; }
        td = (double)term;
        #pragma unroll
        for (int off = 32; off; off >>= 1) td += __shfl_down(td, off);
    }

    if (tid == 0) {
        partials[blockIdx.x] = td;
        __threadfence();                 // release partial
        int v = atomicAdd(cnt, 1);
        isLast = (v == (int)gridDim.x - 1);
    }
    __syncthreads();

    if (isLast) {                        // last-finishing block reduces all
        __threadfence();                 // acquire
        double s = 0.0;
        for (int i = tid; i < (int)gridDim.x; i += THREADS) s += partials[i];
        #pragma unroll
        for (int off = 32; off; off >>= 1) s += __shfl_down(s, off);
        if (lane == 0) redf[wave] = s;
        __syncthreads();
        if (tid == 0) {
            double t = 0.0;
            #pragma unroll
            for (int wv = 0; wv < WAVES; ++wv) t += redf[wv];
            out[0] = (float)t;
        }
    }
}

extern "C" void kernel_launch(void* const* d_in, const int* in_sizes, int n_in,
                              void* d_out, int out_size, void* d_ws, size_t ws_size,
                              hipStream_t stream) {
    const float* A           = (const float*)d_in[0];  // [N, Q, P]
    const float* coeff       = (const float*)d_in[1];  // [N]
    const float* heads_param = (const float*)d_in[2];  // [S, Q, P]
    const float* hr_param    = (const float*)d_in[3];  // [S]
    const int N = in_sizes[1];
    const int nblocks = (N + BLK_ROWS - 1) / BLK_ROWS;  // 1563

    char* ws = (char*)d_ws;
    double* partials = (double*)ws;
    int*   cnt = (int*)(ws + WS_CNT_OFF);
    float* HP  = (float*)(ws + WS_HP_OFF);
    float* hrv = (float*)(ws + WS_HRV_OFF);
    float* out = (float*)d_out;

    const int pre_blocks = (N_S * N_Q + THREADS - 1) / THREADS;  // 13
    precompute_kernel<<<pre_blocks, THREADS, 0, stream>>>(heads_param, hr_param,
                                                          HP, hrv, cnt);
    main_kernel<<<nblocks, THREADS, 0, stream>>>(A, coeff, HP, hrv, partials,
                                                 cnt, out, N);
}